// Round 2
// baseline (7664.140 us; speedup 1.0000x reference)
//
#include <hip/hip_runtime.h>
#include <stdint.h>

// ---------------------------------------------------------------------------
// LLMGRU4rec on MI355X (gfx950)
//   B=128, T=200, LLM=4096, H=256
//   prep    : weights -> f16 frag-major images
//   mlp     : fused fc+gelu, mlp1+gelu, mlp2+gelu, and gi0 = E@Wih0.T + bih0
//   gru     : 8 persistent blocks x 16 batch rows, 200 steps, f16 MFMA
//             matvecs, fp32 gates; h1n(t) saved to ws (logits deferred)
//   logits  : batched tanh(h1_hist @ h2o.T + b) -> OFF1 / OFF4-upper
// ---------------------------------------------------------------------------

typedef _Float16 f16;
typedef _Float16 f16x8 __attribute__((ext_vector_type(8)));
typedef float    f32x4 __attribute__((ext_vector_type(4)));

#define MFMA16(a,b,c) __builtin_amdgcn_mfma_f32_16x16x32_f16((a),(b),(c),0,0,0)

// output segment offsets (fp32 elements) in d_out
#define OFF1 0ull                       // final_output[:, :199, :]  128*199*256
#define OFF2 6520832ull                 // target_pos_embs           128*199*256
#define OFF3 13041664ull                // target_neg_embs           128*199*256
#define OFF4 19562496ull                // concat(E, logits)         128*200*512

__device__ __forceinline__ float geluf(float x){
  return 0.5f * x * (1.0f + erff(x * 0.7071067811865476f));
}
__device__ __forceinline__ float sigmoidf_(float x){
  return 1.0f / (1.0f + expf(-x));
}

// swizzled f16 LDS element offset: XOR the 16B-chunk bits (3..5) with row&7
// -> conflict-free ds_read_b128 of 8-contiguous-k fragments
__device__ __forceinline__ int swz(int row, int k, int rowlen){
  return row * rowlen + (k ^ ((row & 7) << 3));
}

// fragment-major weight image offset (in f16 elements).
// For each (coltile cfrag, kslice kk) a 64-lane x 16B block: a lane's 8
// contiguous K elements for the MFMA B-operand are one coalesced 16B load.
__device__ __forceinline__ size_t frag_off(int cfrag, int kk, int K, int lane){
  return (((size_t)cfrag * (K >> 5) + kk) * 64 + (size_t)lane) * 8;
}

// ---------------------------------------------------------------------------
// prep: W (N,K) fp32 row-major  ->  f16 frag-major image
// ---------------------------------------------------------------------------
__global__ __launch_bounds__(256) void prep_kernel(const float* __restrict__ W,
                                                   f16* __restrict__ img,
                                                   int N, int K){
  int i = blockIdx.x * 256 + threadIdx.x;
  if (i >= N * K) return;
  int col = i / K;
  int k   = i - col * K;
  int ln  = (((k >> 3) & 3) << 4) | (col & 15);   // lane within frag block
  size_t off = frag_off(col >> 4, k >> 5, K, ln) + (size_t)(k & 7);
  img[off] = (f16)W[i];
}

// ---------------------------------------------------------------------------
// Fused MLP: per block, 64 rows x full N=256.
//   L1: K=4096 (LDS-staged A, fp32->f16 convert in flight, double-buffered)
//   L2/L3: K=256 from LDS activation tile
//   int-rows additionally compute gi0 = E @ Wih0.T + bih0 (N=768) -> f16 ws
// ---------------------------------------------------------------------------
__global__ __launch_bounds__(256, 2) void mlp_kernel(
    const float* __restrict__ Xint, const float* __restrict__ Xneg,
    const f16* __restrict__ fcWimg, const float* __restrict__ fcb,
    const f16* __restrict__ W1img,  const float* __restrict__ b1,
    const f16* __restrict__ W2img,  const float* __restrict__ b2,
    const f16* __restrict__ Wih0img,const float* __restrict__ bih0,
    float* __restrict__ out, f16* __restrict__ gi0)
{
  __shared__ f16 Astg[2][64 * 64];    // L1 staging tiles (swizzled)
  __shared__ f16 Aact[64 * 256];      // activation tile (swizzled)

  const int tid  = threadIdx.x;
  const int lane = tid & 63;
  const int wid  = tid >> 6;          // 0..3 : 64-col slice
  const int l15  = lane & 15;
  const int lhi  = lane >> 4;         // 0..3

  const int  bid    = blockIdx.x;
  const bool is_int = (bid < 400);
  const float* X = is_int ? Xint : Xneg;
  const int m0 = (is_int ? bid : bid - 400) * 64;   // row base (relative)

  // ---------------- L1 : K = 4096 ----------------
  f32x4 acc[4][4];
  #pragma unroll
  for (int r = 0; r < 4; ++r)
    #pragma unroll
    for (int c = 0; c < 4; ++c)
      acc[r][c] = (f32x4){0.f, 0.f, 0.f, 0.f};

  // stage tile kt into buffer buf (64 rows x 64 k)
  auto stage = [&](int kt, int buf){
    #pragma unroll
    for (int i = 0; i < 2; ++i){
      int q = tid * 2 + i;
      int row = q >> 3, kc = q & 7;
      const float* src = X + (size_t)(m0 + row) * 4096 + kt * 64 + kc * 8;
      float4 f0 = *(const float4*)src;
      float4 f1 = *(const float4*)(src + 4);
      f16x8 v;
      v[0]=(f16)f0.x; v[1]=(f16)f0.y; v[2]=(f16)f0.z; v[3]=(f16)f0.w;
      v[4]=(f16)f1.x; v[5]=(f16)f1.y; v[6]=(f16)f1.z; v[7]=(f16)f1.w;
      *(f16x8*)&Astg[buf][swz(row, kc * 8, 64)] = v;
    }
  };

  stage(0, 0);
  __syncthreads();

  for (int kt = 0; kt < 64; ++kt){
    const int buf = kt & 1;
    float4 p[2][2];
    if (kt < 63){
      #pragma unroll
      for (int i = 0; i < 2; ++i){
        int q = tid * 2 + i;
        int row = q >> 3, kc = q & 7;
        const float* src = X + (size_t)(m0 + row) * 4096 + (kt + 1) * 64 + kc * 8;
        p[i][0] = *(const float4*)src;
        p[i][1] = *(const float4*)(src + 4);
      }
    }
    #pragma unroll
    for (int s = 0; s < 2; ++s){
      f16x8 a[4], b[4];
      #pragma unroll
      for (int r = 0; r < 4; ++r)
        a[r] = *(const f16x8*)&Astg[buf][swz(r * 16 + l15, s * 32 + lhi * 8, 64)];
      #pragma unroll
      for (int c = 0; c < 4; ++c)
        b[c] = *(const f16x8*)(fcWimg + frag_off(wid * 4 + c, kt * 2 + s, 4096, lane));
      #pragma unroll
      for (int r = 0; r < 4; ++r)
        #pragma unroll
        for (int c = 0; c < 4; ++c)
          acc[r][c] = MFMA16(a[r], b[c], acc[r][c]);
    }
    if (kt < 63){
      #pragma unroll
      for (int i = 0; i < 2; ++i){
        int q = tid * 2 + i;
        int row = q >> 3, kc = q & 7;
        f16x8 v;
        v[0]=(f16)p[i][0].x; v[1]=(f16)p[i][0].y; v[2]=(f16)p[i][0].z; v[3]=(f16)p[i][0].w;
        v[4]=(f16)p[i][1].x; v[5]=(f16)p[i][1].y; v[6]=(f16)p[i][1].z; v[7]=(f16)p[i][1].w;
        *(f16x8*)&Astg[(kt + 1) & 1][swz(row, kc * 8, 64)] = v;
      }
    }
    __syncthreads();
  }

  // L1 epilogue: gelu -> Aact
  #pragma unroll
  for (int r = 0; r < 4; ++r)
    #pragma unroll
    for (int c = 0; c < 4; ++c){
      int col = wid * 64 + c * 16 + l15;
      float bia = fcb[col];
      #pragma unroll
      for (int j = 0; j < 4; ++j){
        int row = r * 16 + lhi * 4 + j;
        Aact[swz(row, col, 256)] = (f16)geluf(acc[r][c][j] + bia);
      }
    }
  __syncthreads();

  // ---------------- L2 : K = 256 ----------------
  {
    f32x4 a2[4][4];
    #pragma unroll
    for (int r = 0; r < 4; ++r)
      #pragma unroll
      for (int c = 0; c < 4; ++c) a2[r][c] = (f32x4){0.f,0.f,0.f,0.f};
    #pragma unroll
    for (int kk = 0; kk < 8; ++kk){
      f16x8 a[4], b[4];
      #pragma unroll
      for (int r = 0; r < 4; ++r)
        a[r] = *(const f16x8*)&Aact[swz(r * 16 + l15, kk * 32 + lhi * 8, 256)];
      #pragma unroll
      for (int c = 0; c < 4; ++c)
        b[c] = *(const f16x8*)(W1img + frag_off(wid * 4 + c, kk, 256, lane));
      #pragma unroll
      for (int r = 0; r < 4; ++r)
        #pragma unroll
        for (int c = 0; c < 4; ++c)
          a2[r][c] = MFMA16(a[r], b[c], a2[r][c]);
    }
    __syncthreads();           // everyone done reading A1
    #pragma unroll
    for (int r = 0; r < 4; ++r)
      #pragma unroll
      for (int c = 0; c < 4; ++c){
        int col = wid * 64 + c * 16 + l15;
        float bia = b1[col];
        #pragma unroll
        for (int j = 0; j < 4; ++j){
          int row = r * 16 + lhi * 4 + j;
          Aact[swz(row, col, 256)] = (f16)geluf(a2[r][c][j] + bia);
        }
      }
    __syncthreads();
  }

  // ---------------- L3 : K = 256, scatter to outputs ----------------
  {
    f32x4 a3[4][4];
    #pragma unroll
    for (int r = 0; r < 4; ++r)
      #pragma unroll
      for (int c = 0; c < 4; ++c) a3[r][c] = (f32x4){0.f,0.f,0.f,0.f};
    #pragma unroll
    for (int kk = 0; kk < 8; ++kk){
      f16x8 a[4], b[4];
      #pragma unroll
      for (int r = 0; r < 4; ++r)
        a[r] = *(const f16x8*)&Aact[swz(r * 16 + l15, kk * 32 + lhi * 8, 256)];
      #pragma unroll
      for (int c = 0; c < 4; ++c)
        b[c] = *(const f16x8*)(W2img + frag_off(wid * 4 + c, kk, 256, lane));
      #pragma unroll
      for (int r = 0; r < 4; ++r)
        #pragma unroll
        for (int c = 0; c < 4; ++c)
          a3[r][c] = MFMA16(a[r], b[c], a3[r][c]);
    }
    __syncthreads();           // done reading A2 before overwriting with E
    #pragma unroll
    for (int r = 0; r < 4; ++r)
      #pragma unroll
      for (int c = 0; c < 4; ++c){
        int col = wid * 64 + c * 16 + l15;
        float bia = b2[col];
        #pragma unroll
        for (int j = 0; j < 4; ++j){
          int row = r * 16 + lhi * 4 + j;
          float v = geluf(a3[r][c][j] + bia);
          int m = m0 + row;
          int bb = m / 200;
          int t  = m - bb * 200;
          if (is_int){
            out[OFF4 + ((size_t)bb * 200 + t) * 512 + col] = v;          // concat lo
            if (t > 0)
              out[OFF2 + ((size_t)bb * 199 + (t - 1)) * 256 + col] = v;  // target_pos
            Aact[swz(row, col, 256)] = (f16)v;                            // E for gi0
          } else {
            if (t < 199)
              out[OFF3 + ((size_t)bb * 199 + t) * 256 + col] = v;        // target_neg
          }
        }
      }
  }

  // ---------------- gi0 = E @ Wih0.T + bih0 (int rows only) ----------------
  if (is_int){
    __syncthreads();           // E tile visible
    for (int pass = 0; pass < 3; ++pass){
      f32x4 g[4][4];
      #pragma unroll
      for (int r = 0; r < 4; ++r)
        #pragma unroll
        for (int c = 0; c < 4; ++c) g[r][c] = (f32x4){0.f,0.f,0.f,0.f};
      #pragma unroll
      for (int kk = 0; kk < 8; ++kk){
        f16x8 a[4], b[4];
        #pragma unroll
        for (int r = 0; r < 4; ++r)
          a[r] = *(const f16x8*)&Aact[swz(r * 16 + l15, kk * 32 + lhi * 8, 256)];
        #pragma unroll
        for (int c = 0; c < 4; ++c)
          b[c] = *(const f16x8*)(Wih0img + frag_off(pass * 16 + wid * 4 + c, kk, 256, lane));
        #pragma unroll
        for (int r = 0; r < 4; ++r)
          #pragma unroll
          for (int c = 0; c < 4; ++c)
            g[r][c] = MFMA16(a[r], b[c], g[r][c]);
      }
      #pragma unroll
      for (int r = 0; r < 4; ++r)
        #pragma unroll
        for (int c = 0; c < 4; ++c){
          int col = pass * 256 + wid * 64 + c * 16 + l15;
          float bia = bih0[col];
          #pragma unroll
          for (int j = 0; j < 4; ++j){
            int m = m0 + r * 16 + lhi * 4 + j;
            gi0[(size_t)m * 768 + col] = (f16)(g[r][c][j] + bia);
          }
        }
    }
  }
}

// ---------------------------------------------------------------------------
// GRU: 8 persistent blocks x 16 batch rows, 512 thr (8 waves).
// Wave `wid` owns h-columns [wid*32, wid*32+32). Per step:
//   P0: gh0 matvecs (r/z/n); in-register gate math -> h0n
//   P1: gi1/gh1 matvecs (6 accs); gate math -> h1n, saved to h1hist (f16)
// State: unmasked h0n/h1n in double-buffered swizzled f16 LDS; fp32 carry in
// registers. Mask m_{t-1} folded as a row scalar on the matvec result and the
// z*h term. h2o logits are deferred to logits_kernel (removes 128KB/step of
// weight streaming from the sequential chain).
// ---------------------------------------------------------------------------
__global__ __launch_bounds__(512) void gru_kernel(
    const f16* __restrict__ gi0,  const int* __restrict__ mask,
    const f16* __restrict__ Whh0img, const float* __restrict__ bhh0,
    const f16* __restrict__ Wih1img, const float* __restrict__ bih1,
    const f16* __restrict__ Whh1img, const float* __restrict__ bhh1,
    f16* __restrict__ h1hist)
{
  __shared__ f16 h0s[2][16 * 256];
  __shared__ f16 h1s[2][16 * 256];

  const int tid  = threadIdx.x;
  const int lane = tid & 63;
  const int wid  = tid >> 6;      // 0..7
  const int l15  = lane & 15;
  const int lhi  = lane >> 4;     // 0..3
  const int bg   = blockIdx.x;    // batch group: rows bg*16 .. bg*16+15

  for (int i = tid; i < 16 * 256; i += 512){
    h0s[0][i] = (f16)0.f; h0s[1][i] = (f16)0.f;
    h1s[0][i] = (f16)0.f; h1s[1][i] = (f16)0.f;
  }

  int colt[2];
  colt[0] = wid * 32 + l15;
  colt[1] = colt[0] + 16;
  float cb_hh0[2][3], cb_ih1[2][3], cb_hh1[2][3];
  #pragma unroll
  for (int tt = 0; tt < 2; ++tt){
    int c = colt[tt];
    cb_hh0[tt][0]=bhh0[c]; cb_hh0[tt][1]=bhh0[256+c]; cb_hh0[tt][2]=bhh0[512+c];
    cb_ih1[tt][0]=bih1[c]; cb_ih1[tt][1]=bih1[256+c]; cb_ih1[tt][2]=bih1[512+c];
    cb_hh1[tt][0]=bhh1[c]; cb_hh1[tt][1]=bhh1[256+c]; cb_hh1[tt][2]=bhh1[512+c];
  }
  float h0p[2][4] = {{0.f,0.f,0.f,0.f},{0.f,0.f,0.f,0.f}};
  float h1p[2][4] = {{0.f,0.f,0.f,0.f},{0.f,0.f,0.f,0.f}};
  __syncthreads();

  for (int t = 0; t < 200; ++t){
    const int cur = t & 1, prv = cur ^ 1;

    float mp[4];
    #pragma unroll
    for (int j = 0; j < 4; ++j){
      int b = bg * 16 + lhi * 4 + j;
      mp[j] = (t == 0) ? 1.0f : (mask[b * 200 + (t - 1)] ? 1.0f : 0.0f);
    }
    // this step's precomputed gi0 (issued early, consumed post-MFMA)
    float gi[2][3][4];
    #pragma unroll
    for (int tt = 0; tt < 2; ++tt)
      #pragma unroll
      for (int j = 0; j < 4; ++j){
        int b = bg * 16 + lhi * 4 + j;
        size_t gb = ((size_t)b * 200 + t) * 768 + colt[tt];
        gi[tt][0][j] = (float)gi0[gb];
        gi[tt][1][j] = (float)gi0[gb + 256];
        gi[tt][2][j] = (float)gi0[gb + 512];
      }

    // ---- P0 ----
    f16x8 a0[8], a1[8];
    #pragma unroll
    for (int kk = 0; kk < 8; ++kk){
      a0[kk] = *(const f16x8*)&h0s[prv][swz(l15, kk * 32 + lhi * 8, 256)];
      a1[kk] = *(const f16x8*)&h1s[prv][swz(l15, kk * 32 + lhi * 8, 256)];
    }
    f32x4 ar[2], az[2], an[2];
    #pragma unroll
    for (int tt = 0; tt < 2; ++tt){
      ar[tt]=(f32x4){0.f,0.f,0.f,0.f}; az[tt]=ar[tt]; an[tt]=ar[tt];
    }
    #pragma unroll
    for (int tt = 0; tt < 2; ++tt){
      int cf = wid * 2 + tt;
      #pragma unroll
      for (int kk = 0; kk < 8; ++kk){
        f16x8 br = *(const f16x8*)(Whh0img + frag_off(cf,      kk, 256, lane));
        f16x8 bz = *(const f16x8*)(Whh0img + frag_off(16 + cf, kk, 256, lane));
        f16x8 bn = *(const f16x8*)(Whh0img + frag_off(32 + cf, kk, 256, lane));
        ar[tt] = MFMA16(a0[kk], br, ar[tt]);
        az[tt] = MFMA16(a0[kk], bz, az[tt]);
        an[tt] = MFMA16(a0[kk], bn, an[tt]);
      }
    }
    // layer-0 gates in registers
    #pragma unroll
    for (int tt = 0; tt < 2; ++tt)
      #pragma unroll
      for (int j = 0; j < 4; ++j){
        float r = sigmoidf_(gi[tt][0][j] + mp[j] * ar[tt][j] + cb_hh0[tt][0]);
        float z = sigmoidf_(gi[tt][1][j] + mp[j] * az[tt][j] + cb_hh0[tt][1]);
        float n = tanhf   (gi[tt][2][j] + r * (mp[j] * an[tt][j] + cb_hh0[tt][2]));
        float h = (1.0f - z) * n + z * (mp[j] * h0p[tt][j]);
        h0p[tt][j] = h;                                   // unmasked carry
        h0s[cur][swz(lhi * 4 + j, colt[tt], 256)] = (f16)h;
      }
    __syncthreads();

    // ---- P1 ----
    f16x8 n0[8];
    #pragma unroll
    for (int kk = 0; kk < 8; ++kk)
      n0[kk] = *(const f16x8*)&h0s[cur][swz(l15, kk * 32 + lhi * 8, 256)];
    f32x4 ri[2], rh[2], zi[2], zh[2], ni[2], nh[2];
    #pragma unroll
    for (int tt = 0; tt < 2; ++tt){
      ri[tt]=(f32x4){0.f,0.f,0.f,0.f};
      rh[tt]=ri[tt]; zi[tt]=ri[tt]; zh[tt]=ri[tt]; ni[tt]=ri[tt]; nh[tt]=ri[tt];
    }
    #pragma unroll
    for (int tt = 0; tt < 2; ++tt){
      int cf = wid * 2 + tt;
      #pragma unroll
      for (int kk = 0; kk < 8; ++kk){
        f16x8 bri = *(const f16x8*)(Wih1img + frag_off(cf,      kk, 256, lane));
        f16x8 brh = *(const f16x8*)(Whh1img + frag_off(cf,      kk, 256, lane));
        f16x8 bzi = *(const f16x8*)(Wih1img + frag_off(16 + cf, kk, 256, lane));
        f16x8 bzh = *(const f16x8*)(Whh1img + frag_off(16 + cf, kk, 256, lane));
        f16x8 bni = *(const f16x8*)(Wih1img + frag_off(32 + cf, kk, 256, lane));
        f16x8 bnh = *(const f16x8*)(Whh1img + frag_off(32 + cf, kk, 256, lane));
        ri[tt] = MFMA16(n0[kk], bri, ri[tt]);
        rh[tt] = MFMA16(a1[kk], brh, rh[tt]);
        zi[tt] = MFMA16(n0[kk], bzi, zi[tt]);
        zh[tt] = MFMA16(a1[kk], bzh, zh[tt]);
        ni[tt] = MFMA16(n0[kk], bni, ni[tt]);
        nh[tt] = MFMA16(a1[kk], bnh, nh[tt]);
      }
    }
    #pragma unroll
    for (int tt = 0; tt < 2; ++tt)
      #pragma unroll
      for (int j = 0; j < 4; ++j){
        float r = sigmoidf_(ri[tt][j] + cb_ih1[tt][0] + mp[j] * rh[tt][j] + cb_hh1[tt][0]);
        float z = sigmoidf_(zi[tt][j] + cb_ih1[tt][1] + mp[j] * zh[tt][j] + cb_hh1[tt][1]);
        float n = tanhf   (ni[tt][j] + cb_ih1[tt][2] + r * (mp[j] * nh[tt][j] + cb_hh1[tt][2]));
        float h = (1.0f - z) * n + z * (mp[j] * h1p[tt][j]);
        h1p[tt][j] = h;
        h1s[cur][swz(lhi * 4 + j, colt[tt], 256)] = (f16)h;
        int b = bg * 16 + lhi * 4 + j;
        h1hist[((size_t)b * 200 + t) * 256 + colt[tt]] = (f16)h;   // unmasked
      }
    __syncthreads();
  }
}

// ---------------------------------------------------------------------------
// logits = tanh(h1hist @ h2o.T + b) for all 25600 rows; scatter to OFF1/OFF4.
// A-fragments read straight from global (no LDS needed at K=256).
// ---------------------------------------------------------------------------
__global__ __launch_bounds__(256) void logits_kernel(
    const f16* __restrict__ h1hist, const f16* __restrict__ h2oimg,
    const float* __restrict__ h2ob, float* __restrict__ out)
{
  const int tid  = threadIdx.x;
  const int lane = tid & 63;
  const int wid  = tid >> 6;
  const int l15  = lane & 15;
  const int lhi  = lane >> 4;
  const int m0   = blockIdx.x * 64;

  f32x4 acc[4][4];
  #pragma unroll
  for (int r = 0; r < 4; ++r)
    #pragma unroll
    for (int c = 0; c < 4; ++c) acc[r][c] = (f32x4){0.f,0.f,0.f,0.f};

  #pragma unroll
  for (int kk = 0; kk < 8; ++kk){
    f16x8 a[4], b[4];
    #pragma unroll
    for (int r = 0; r < 4; ++r)
      a[r] = *(const f16x8*)&h1hist[(size_t)(m0 + r * 16 + l15) * 256 + kk * 32 + lhi * 8];
    #pragma unroll
    for (int c = 0; c < 4; ++c)
      b[c] = *(const f16x8*)(h2oimg + frag_off(wid * 4 + c, kk, 256, lane));
    #pragma unroll
    for (int r = 0; r < 4; ++r)
      #pragma unroll
      for (int c = 0; c < 4; ++c)
        acc[r][c] = MFMA16(a[r], b[c], acc[r][c]);
  }

  #pragma unroll
  for (int r = 0; r < 4; ++r)
    #pragma unroll
    for (int c = 0; c < 4; ++c){
      int col = wid * 64 + c * 16 + l15;
      float bia = h2ob[col];
      #pragma unroll
      for (int j = 0; j < 4; ++j){
        int m = m0 + r * 16 + lhi * 4 + j;
        int bb = m / 200;
        int t  = m - bb * 200;
        float v = tanhf(acc[r][c][j] + bia);
        out[OFF4 + ((size_t)bb * 200 + t) * 512 + 256 + col] = v;
        if (t < 199)
          out[OFF1 + ((size_t)bb * 199 + t) * 256 + col] = v;
      }
    }
}

// ---------------------------------------------------------------------------
extern "C" void kernel_launch(void* const* d_in, const int* in_sizes, int n_in,
                              void* d_out, int out_size, void* d_ws, size_t ws_size,
                              hipStream_t stream)
{
  const float* Xint = (const float*)d_in[0];
  const int*   msk  = (const int*)  d_in[1];
  const float* Xneg = (const float*)d_in[2];
  const float* fcW  = (const float*)d_in[3];
  const float* fcb  = (const float*)d_in[4];
  const float* W1   = (const float*)d_in[5];
  const float* b1   = (const float*)d_in[6];
  const float* W2   = (const float*)d_in[7];
  const float* b2   = (const float*)d_in[8];
  const float* Wih0 = (const float*)d_in[9];
  const float* Whh0 = (const float*)d_in[10];
  const float* bih0 = (const float*)d_in[11];
  const float* bhh0 = (const float*)d_in[12];
  const float* Wih1 = (const float*)d_in[13];
  const float* Whh1 = (const float*)d_in[14];
  const float* bih1 = (const float*)d_in[15];
  const float* bhh1 = (const float*)d_in[16];
  const float* h2oW = (const float*)d_in[17];
  const float* h2ob = (const float*)d_in[18];
  float* out = (float*)d_out;

  // workspace layout (f16 elements): frag-major weight images + gi0 + h1hist
  f16* fcWimg  = (f16*)d_ws;              // 256x4096  = 1048576
  f16* W1img   = fcWimg  + 1048576;       // 256x256   = 65536
  f16* W2img   = W1img   + 65536;
  f16* Wih0img = W2img   + 65536;         // 768x256   = 196608
  f16* Whh0img = Wih0img + 196608;
  f16* Wih1img = Whh0img + 196608;
  f16* Whh1img = Wih1img + 196608;
  f16* h2oimg  = Whh1img + 196608;        // 256x256   = 65536
  f16* gi0     = h2oimg  + 65536;         // 25600x768 = 19660800
  f16* h1hist  = gi0     + 19660800;      // 25600x256 = 6553600

  prep_kernel<<<4096, 256, 0, stream>>>(fcW,  fcWimg,  256, 4096);
  prep_kernel<<<256,  256, 0, stream>>>(W1,   W1img,   256, 256);
  prep_kernel<<<256,  256, 0, stream>>>(W2,   W2img,   256, 256);
  prep_kernel<<<768,  256, 0, stream>>>(Wih0, Wih0img, 768, 256);
  prep_kernel<<<768,  256, 0, stream>>>(Whh0, Whh0img, 768, 256);
  prep_kernel<<<768,  256, 0, stream>>>(Wih1, Wih1img, 768, 256);
  prep_kernel<<<768,  256, 0, stream>>>(Whh1, Whh1img, 768, 256);
  prep_kernel<<<256,  256, 0, stream>>>(h2oW, h2oimg,  256, 256);

  mlp_kernel<<<800, 256, 0, stream>>>(Xint, Xneg, fcWimg, fcb, W1img, b1,
                                      W2img, b2, Wih0img, bih0, out, gi0);
  gru_kernel<<<8, 512, 0, stream>>>(gi0, msk, Whh0img, bhh0, Wih1img, bih1,
                                    Whh1img, bhh1, h1hist);
  logits_kernel<<<400, 256, 0, stream>>>(h1hist, h2oimg, h2ob, out);
}